// Round 18
// baseline (415.353 us; speedup 1.0000x reference)
//
#include <hip/hip_runtime.h>

typedef unsigned short u16;
typedef __bf16 bf16x8 __attribute__((ext_vector_type(8)));
typedef float f32x4 __attribute__((ext_vector_type(4)));
typedef u16 u16x8 __attribute__((ext_vector_type(8)));
typedef u16 u16x4 __attribute__((ext_vector_type(4)));
typedef unsigned u32x4 __attribute__((ext_vector_type(4)));

__device__ __forceinline__ u16 f2bf(float f) {
    union { float f; unsigned u; } v; v.f = f;
    unsigned r = v.u + 0x7FFFu + ((v.u >> 16) & 1u);
    return (u16)(r >> 16);
}
__device__ __forceinline__ float bf2f(u16 u) {
    union { unsigned u; float f; } v; v.u = ((unsigned)u) << 16; return v.f;
}
__device__ __forceinline__ unsigned cvt_pk_bf16(float lo, float hi) {
    unsigned r;
    asm("v_cvt_pk_bf16_f32 %0, %1, %2" : "=v"(r) : "v"(lo), "v"(hi));
    return r;
}

#define AS1 __attribute__((address_space(1)))
#define AS3 __attribute__((address_space(3)))
__device__ __forceinline__ void gload_lds16(const void* g, void* l) {
    __builtin_amdgcn_global_load_lds((const AS1 void*)(g), (AS3 void*)(l), 16, 0, 0);
}

// Panel layout (128-row blocks): [panel = R>>7][ktile = k>>5][row = R&127][kk = k&31]

// ---------------- prep: roll(-6,-6) + window partition + cast + PANELIZE (8 elems/thread) ----------------
__global__ __launch_bounds__(256) void prep_x_kernel(const float* __restrict__ x, u16* __restrict__ xw) {
    unsigned i = ((unsigned)blockIdx.x * 256u + threadIdx.x) * 8u;
    int R = (int)(i / 768u); int c = (int)(i % 768u);
    int w = R / 144, nn = R - w * 144;
    int b = w >> 2, wi = w & 3;
    int r = nn / 12, cc = nn - r * 12;
    int sh = (wi >> 1) * 12 + r + 6; if (sh >= 24) sh -= 24;
    int sw = (wi & 1) * 12 + cc + 6; if (sw >= 24) sw -= 24;
    const float* src = x + (((size_t)b * 24 + sh) * 24 + sw) * 768 + c;
    f32x4 v0 = *(const f32x4*)src;
    f32x4 v1 = *(const f32x4*)(src + 4);
    u16x8 o;
    o[0] = f2bf(v0[0]); o[1] = f2bf(v0[1]); o[2] = f2bf(v0[2]); o[3] = f2bf(v0[3]);
    o[4] = f2bf(v1[0]); o[5] = f2bf(v1[1]); o[6] = f2bf(v1[2]); o[7] = f2bf(v1[3]);
    size_t idx = ((size_t)(R >> 7) * 24 + (c >> 5)) * 4096 + (R & 127) * 32 + (c & 31);
    *(u16x8*)(xw + idx) = o;
}

// ---------------- weight transpose + cast + panelize ----------------
__global__ __launch_bounds__(256) void transpose_cast_kernel(const float* __restrict__ w, u16* __restrict__ wt,
                                                             int K, int N) {
    __shared__ float tile[32][33];
    int tx = threadIdx.x & 31, ty = threadIdx.x >> 5;
    int nb = blockIdx.x * 32, kb = blockIdx.y * 32;
#pragma unroll
    for (int rr = 0; rr < 32; rr += 8) tile[rr + ty][tx] = w[(size_t)(kb + rr + ty) * N + nb + tx];
    __syncthreads();
#pragma unroll
    for (int rr = 0; rr < 32; rr += 8) {
        int n = nb + rr + ty, k = kb + tx;
        wt[((size_t)(n >> 7) * 24 + (k >> 5)) * 4096 + (n & 127) * 32 + (k & 31)] = f2bf(tile[tx][rr + ty]);
    }
}

// ---------- bmm[wi][h][m][n] = bf16( rpb[rel[n*144+m]][h] + mask(n,m,wi) ), m=k, n=q ----------
__global__ __launch_bounds__(256) void make_bmm_kernel(const float* __restrict__ tab, const int* __restrict__ rel,
                                                       u16* __restrict__ bmm) {
    int i = blockIdx.x * 256 + threadIdx.x;
    if (i >= 1990656) return;
    int wiH = i / 20736, mn = i - wiH * 20736;
    int wi = wiH / 24, h = wiH - wi * 24;
    int m = mn / 144, n = mn - m * 144;
    int wh = wi >> 1, ww = wi & 1;
    int rn = n / 12, cn = n - rn * 12;
    int rm = m / 12, cm = m - rm * 12;
    int regn = (wh ? (rn < 6 ? 1 : 2) : 0) * 3 + (ww ? (cn < 6 ? 1 : 2) : 0);
    int regm = (wh ? (rm < 6 ? 1 : 2) : 0) * 3 + (ww ? (cm < 6 ? 1 : 2) : 0);
    float v = tab[rel[n * 144 + m] * 24 + h];
    if (regn != regm) v -= 100.0f;
    bmm[i] = f2bf(v);
}

// ------- 128x128 BK=32, 4 waves, 3 buffers x 16KB, 3 blocks/CU, depth-2, PERSISTENT tiles -------
#define FENCE asm volatile("" ::: "memory")
#define BARRIER __builtin_amdgcn_s_barrier()

#define STAGE_TILE(gp, ldsoff)                                                                 \
    { const char* srcb = (const char*)(gp);                                                    \
      _Pragma("unroll") for (int j = 0; j < 2; j++) {                                          \
        int off = j * 4096 + t * 16;                                                           \
        gload_lds16(srcb + off, (char*)lds + (ldsoff) + off);                                  \
    } }

template <int EPI>
__global__ __launch_bounds__(256, 3) void gemm128_kernel(const u16* __restrict__ A, const u16* __restrict__ Bt,
                                                         const float* __restrict__ bias,
                                                         u16* __restrict__ o0, u16* __restrict__ o1, u16* __restrict__ o2,
                                                         int Ndim, int Kdim, int nxb, int ntiles, float qscale) {
    __shared__ __align__(16) u16 lds[24576];
    const int t = threadIdx.x, lane = t & 63, wv = t >> 6;
    const int wr = wv >> 1, wc = wv & 1;
    const int l15 = lane & 15, lg = lane >> 4;
    const int NT = Kdim >> 5;
    const int q8 = ntiles >> 3, r8 = ntiles & 7;

    int tid = blockIdx.x;
    int xcd = tid & 7, loc = tid >> 3;
    int wg = (xcd < r8 ? xcd * (q8 + 1) : r8 * (q8 + 1) + (xcd - r8) * q8) + loc;
    int by = wg / nxb, bx = wg - by * nxb;
    const u16* Ap = A + (size_t)by * NT * 4096;
    const u16* Bp = Bt + (size_t)bx * NT * 4096;

    STAGE_TILE(Ap, 0);
    STAGE_TILE(Bp, 8192);
    STAGE_TILE(Ap + 4096, 16384);
    STAGE_TILE(Bp + 4096, 16384 + 8192);
    asm volatile("s_waitcnt vmcnt(4)" ::: "memory");
    FENCE; BARRIER;

    while (true) {
        f32x4 acc[4][4] = {};
        int ntid = tid + (int)gridDim.x;
        bool hasNext = ntid < ntiles;
        int nby = 0, nbx = 0;
        const u16 *Anp = nullptr, *Bnp = nullptr;
        if (hasNext) {
            int nxcd = ntid & 7, nloc = ntid >> 3;
            int nwg = (nxcd < r8 ? nxcd * (q8 + 1) : r8 * (q8 + 1) + (nxcd - r8) * q8) + nloc;
            nby = nwg / nxb; nbx = nwg - nby * nxb;
            Anp = A + (size_t)nby * NT * 4096;
            Bnp = Bt + (size_t)nbx * NT * 4096;
        }
        for (int T = 0; T < NT; ++T) {
            const char* rb = (const char*)lds + (T % 3) * 16384;
            const int sb = ((T + 2) % 3) * 16384;
            bool st = true;
            if (T + 2 < NT) {
                STAGE_TILE(Ap + (T + 2) * 4096, sb);
                STAGE_TILE(Bp + (T + 2) * 4096, sb + 8192);
            } else if (hasNext) {
                int TT = T + 2 - NT;
                STAGE_TILE(Anp + TT * 4096, sb);
                STAGE_TILE(Bnp + TT * 4096, sb + 8192);
            } else st = false;
            bf16x8 aR[4], bR[4];
#pragma unroll
            for (int mf = 0; mf < 4; mf++)
                aR[mf] = *(const bf16x8*)(rb + (wr * 64 + mf * 16 + l15) * 64 + lg * 16);
#pragma unroll
            for (int nf = 0; nf < 4; nf++)
                bR[nf] = *(const bf16x8*)(rb + 8192 + (wc * 64 + nf * 16 + l15) * 64 + lg * 16);
            __builtin_amdgcn_s_setprio(1);
#pragma unroll
            for (int mf = 0; mf < 4; mf++)
#pragma unroll
                for (int nf = 0; nf < 4; nf++)
                    acc[mf][nf] = __builtin_amdgcn_mfma_f32_16x16x32_bf16(aR[mf], bR[nf], acc[mf][nf], 0, 0, 0);
            __builtin_amdgcn_s_setprio(0);
            if (T < NT - 1 || hasNext) {
                if (st) { asm volatile("s_waitcnt vmcnt(4)" ::: "memory"); }
                else    { asm volatile("s_waitcnt vmcnt(0)" ::: "memory"); }
                FENCE; BARRIER;
            }
        }
        const int bm = by << 7, bn = bx << 7;
#pragma unroll
        for (int mf = 0; mf < 4; mf++) {
            int Rbase = bm + wr * 64 + mf * 16 + lg * 4;
#pragma unroll
            for (int nf = 0; nf < 4; nf++) {
                int Cg = bn + wc * 64 + nf * 16 + l15;
                float bv = bias[Cg];
                if (EPI == 0) {
                    int s = Cg / 768; int rem = Cg - s * 768; int h = rem >> 5; int dd = rem & 31;
#pragma unroll
                    for (int rg = 0; rg < 4; rg++) {
                        int R = Rbase + rg;
                        int w2 = R / 144; int nn = R - w2 * 144;
                        float v = acc[mf][nf][rg] + bv;
                        if (s == 0)      o0[((size_t)(w2 * 24 + h) * 144 + nn) * 32 + dd] = f2bf(v * qscale);
                        else if (s == 1) o1[((size_t)(w2 * 24 + h) * 144 + nn) * 32 + dd] = f2bf(v);
                        else             o2[((size_t)(w2 * 24 + h) * 32 + dd) * 144 + nn] = f2bf(v);
                    }
                } else {
#pragma unroll
                    for (int rg = 0; rg < 4; rg++) {
                        int R = Rbase + rg;
                        o0[(size_t)R * Ndim + Cg] = f2bf(acc[mf][nf][rg] + bv);
                    }
                }
            }
        }
        if (!hasNext) break;
        tid = ntid; by = nby; bx = nbx; Ap = Anp; Bp = Bnp;
    }
}

// ---- fused window attention, SWAPPED operands; bias+mask pre-fused; Q hoisted; setprio on MFMA ----
__global__ __launch_bounds__(192) void attn_kernel(const u16* __restrict__ Qg, const u16* __restrict__ Kg,
                                                   const u16* __restrict__ Vg, const u16* __restrict__ bmm,
                                                   u16* __restrict__ Ob) {
    __shared__ __align__(16) u16 Ks[144 * 40];
    __shared__ __align__(16) u16 Vs[32 * 160];
    const int bx = blockIdx.x;
    const int w = bx / 24, h = bx - w * 24;
    const int wi = w & 3;
    const int t = threadIdx.x, lane = t & 63, wv = t >> 6;
    const int l15 = lane & 15, lg = lane >> 4;
    const size_t base = (size_t)bx * 4608;
    // hoist all 3 q-stripe fragments: latency hides under K/V staging + barrier
    bf16x8 aqv[3];
#pragma unroll
    for (int it = 0; it < 3; ++it) {
        int q = (wv * 3 + it) * 16 + l15;
        aqv[it] = *(const bf16x8*)(Qg + base + (size_t)q * 32 + lg * 8);
    }
#pragma unroll
    for (int p = 0; p < 3; p++) {
        int e = t + p * 192;
        int row = e >> 2, cx = (e & 3) << 3;
        *(u16x8*)(Ks + row * 40 + cx) = *(const u16x8*)(Kg + base + row * 32 + cx);
        int rv = e / 18, cv = (e - rv * 18) * 8;
        int ba = (rv * 320 + cv * 2) ^ ((rv & 7) << 4);
        *(u16x8*)((char*)Vs + ba) = *(const u16x8*)(Vg + base + rv * 144 + cv);
    }
    if (t < 64) {
        u16x8 zz = (u16x8)0;
        int rv = t >> 1, cv = 144 + (t & 1) * 8;
        int ba = (rv * 320 + cv * 2) ^ ((rv & 7) << 4);
        *(u16x8*)((char*)Vs + ba) = zz;
    }
    __syncthreads();

    const u16* bh = bmm + (size_t)(wi * 24 + h) * 20736;
#pragma unroll 1
    for (int it = 0; it < 3; ++it) {
        const int s = wv * 3 + it;
        const int q = s * 16 + l15;
        bf16x8 aq = aqv[it];
        f32x4 S[9];
        {
            f32x4 z4 = (f32x4)0.0f;
            __builtin_amdgcn_s_setprio(1);
#pragma unroll
            for (int j = 0; j < 9; j++) {
                bf16x8 bk = *(const bf16x8*)(Ks + (j * 16 + l15) * 40 + lg * 8);
                S[j] = __builtin_amdgcn_mfma_f32_16x16x32_bf16(bk, aq, z4, 0, 0, 0);
            }
            __builtin_amdgcn_s_setprio(0);
        }
        float mx = -1e30f;
#pragma unroll
        for (int j = 0; j < 9; j++) {
            const u16* bj = bh + (j * 16 + lg * 4) * 144 + q;
#pragma unroll
            for (int rg = 0; rg < 4; rg++) {
                float v = S[j][rg] + bf2f(bj[rg * 144]);
                S[j][rg] = v;
                mx = fmaxf(mx, v);
            }
        }
        mx = fmaxf(mx, __shfl_xor(mx, 16));
        mx = fmaxf(mx, __shfl_xor(mx, 32));
        float sum = 0.0f;
#pragma unroll
        for (int j = 0; j < 9; j++) {
#pragma unroll
            for (int rg = 0; rg < 4; rg++) { float e = __expf(S[j][rg] - mx); S[j][rg] = e; sum += e; }
        }
        sum += __shfl_xor(sum, 16);
        sum += __shfl_xor(sum, 32);
        float inv = 1.0f / sum;
        unsigned pk[10][2];
#pragma unroll
        for (int j = 0; j < 9; j++) {
            pk[j][0] = cvt_pk_bf16(S[j][0], S[j][1]);
            pk[j][1] = cvt_pk_bf16(S[j][2], S[j][3]);
        }
        pk[9][0] = 0; pk[9][1] = 0;
        f32x4 o0 = (f32x4)0.0f, o1 = (f32x4)0.0f;
        const int srcA = 32 * (lg & 1) + l15;
        const int srcB = srcA + 16;
        const bool lowj = (lg < 2);
#pragma unroll
        for (int ks = 0; ks < 5; ks++) {
            const int j0 = 2 * ks, j1 = 2 * ks + 1;
            unsigned a0 = __shfl(pk[j0][0], srcA), a1 = __shfl(pk[j0][1], srcA);
            unsigned a2 = __shfl(pk[j0][0], srcB), a3 = __shfl(pk[j0][1], srcB);
            unsigned b0 = __shfl(pk[j1][0], srcA), b1 = __shfl(pk[j1][1], srcA);
            unsigned b2 = __shfl(pk[j1][0], srcB), b3 = __shfl(pk[j1][1], srcB);
            u32x4 pw;
            pw[0] = lowj ? a0 : b0; pw[1] = lowj ? a1 : b1;
            pw[2] = lowj ? a2 : b2; pw[3] = lowj ? a3 : b3;
            bf16x8 pb = *(const bf16x8*)&pw;
            int k2 = (ks * 32 + lg * 8) * 2;
            int rv0 = l15, rv1 = 16 + l15;
            bf16x8 v0 = *(const bf16x8*)((char*)Vs + ((rv0 * 320 + k2) ^ ((rv0 & 7) << 4)));
            bf16x8 v1 = *(const bf16x8*)((char*)Vs + ((rv1 * 320 + k2) ^ ((rv1 & 7) << 4)));
            __builtin_amdgcn_s_setprio(1);
            o0 = __builtin_amdgcn_mfma_f32_16x16x32_bf16(v0, pb, o0, 0, 0, 0);
            o1 = __builtin_amdgcn_mfma_f32_16x16x32_bf16(v1, pb, o1, 0, 0, 0);
            __builtin_amdgcn_s_setprio(0);
        }
        int R = w * 144 + q;
        size_t idx = ((size_t)(R >> 7) * 24 + h) * 4096 + (R & 127) * 32 + lg * 4;
        u16x4 w0, w1;
#pragma unroll
        for (int rg = 0; rg < 4; rg++) { w0[rg] = f2bf(o0[rg] * inv); w1[rg] = f2bf(o1[rg] * inv); }
        *(u16x4*)(Ob + idx) = w0;
        *(u16x4*)(Ob + idx + 16) = w1;
    }
}

// ---------------- L2 norm (bf16 input) + window-merge + reverse shift ----------------
__global__ __launch_bounds__(256) void norm_kernel(const u16* __restrict__ raw, float* __restrict__ out) {
    int R = blockIdx.x * 4 + (threadIdx.x >> 6);
    int lane = threadIdx.x & 63;
    const u16* src = raw + (size_t)R * 768;
    u16x8 a = *(const u16x8*)(src + lane * 8);
    u16x4 b = *(const u16x4*)(src + 512 + lane * 4);
    float f[12];
#pragma unroll
    for (int k = 0; k < 8; k++) f[k] = bf2f(a[k]);
#pragma unroll
    for (int k = 0; k < 4; k++) f[8 + k] = bf2f(b[k]);
    float ss = 0.0f;
#pragma unroll
    for (int k = 0; k < 12; k++) ss += f[k] * f[k];
#pragma unroll
    for (int d = 1; d < 64; d <<= 1) ss += __shfl_xor(ss, d);
    float inv = 1.0f / sqrtf(ss + 1e-6f);
    int w = R / 144, nn = R - w * 144;
    int bb = w >> 2, wi = w & 3;
    int r = nn / 12, cc = nn - r * 12;
    int oh = (wi >> 1) * 12 + r + 6; if (oh >= 24) oh -= 24;
    int ow = (wi & 1) * 12 + cc + 6; if (ow >= 24) ow -= 24;
    float* dst = out + (((size_t)bb * 24 + oh) * 24 + ow) * 768;
    f32x4 v0, v1, v2;
#pragma unroll
    for (int k = 0; k < 4; k++) { v0[k] = f[k] * inv; v1[k] = f[4 + k] * inv; v2[k] = f[8 + k] * inv; }
    *(f32x4*)(dst + lane * 8) = v0;
    *(f32x4*)(dst + lane * 8 + 4) = v1;
    *(f32x4*)(dst + 512 + lane * 4) = v2;
}

extern "C" void kernel_launch(void* const* d_in, const int* in_sizes, int n_in,
                              void* d_out, int out_size, void* d_ws, size_t ws_size,
                              hipStream_t stream) {
    const float* x      = (const float*)d_in[0];
    const float* qkv_w  = (const float*)d_in[1];
    const float* qkv_b  = (const float*)d_in[2];
    const float* proj_w = (const float*)d_in[3];
    const float* proj_b = (const float*)d_in[4];
    const float* rpb    = (const float*)d_in[5];
    const int*   rel    = (const int*)d_in[6];

    char* ws = (char*)d_ws;
    const size_t SZ = 56623104;  // 36864*768*2 bytes
    u16*   xw   = (u16*)(ws);
    u16*   Qb   = (u16*)(ws + SZ);
    u16*   Kb   = (u16*)(ws + 2 * SZ);
    u16*   Vt   = (u16*)(ws + 3 * SZ);
    u16*   Ob   = (u16*)(ws + 4 * SZ);
    u16*   qwt  = (u16*)(ws + 5 * SZ);
    u16*   pwt  = (u16*)(ws + 5 * SZ + 3538944);
    u16*   bmm  = (u16*)(ws);   // built AFTER QKV GEMM into dead xw space
    u16*   raw16 = (u16*)(ws);  // aliases bmm/xw (dead by GEMM2)

    prep_x_kernel<<<13824, 256, 0, stream>>>(x, xw);
    transpose_cast_kernel<<<dim3(72, 24), 256, 0, stream>>>(qkv_w, qwt, 768, 2304);
    transpose_cast_kernel<<<dim3(24, 24), 256, 0, stream>>>(proj_w, pwt, 768, 768);

    gemm128_kernel<0><<<768, 256, 0, stream>>>(xw, qwt, qkv_b, Qb, Kb, Vt,
                                               2304, 768, 18, 5184, 0.17677669529663687f);
    make_bmm_kernel<<<7776, 256, 0, stream>>>(rpb, rel, bmm);
    attn_kernel<<<6144, 192, 0, stream>>>(Qb, Kb, Vt, bmm, Ob);
    gemm128_kernel<1><<<768, 256, 0, stream>>>(Ob, pwt, proj_b, raw16, nullptr, nullptr,
                                               768, 768, 6, 1728, 1.0f);
    norm_kernel<<<9216, 256, 0, stream>>>(raw16, (float*)d_out);
}

// Round 19
// 390.800 us; speedup vs baseline: 1.0628x; 1.0628x over previous
//
#include <hip/hip_runtime.h>

typedef unsigned short u16;
typedef __bf16 bf16x8 __attribute__((ext_vector_type(8)));
typedef float f32x4 __attribute__((ext_vector_type(4)));
typedef u16 u16x8 __attribute__((ext_vector_type(8)));
typedef u16 u16x4 __attribute__((ext_vector_type(4)));
typedef unsigned u32x4 __attribute__((ext_vector_type(4)));

__device__ __forceinline__ u16 f2bf(float f) {
    union { float f; unsigned u; } v; v.f = f;
    unsigned r = v.u + 0x7FFFu + ((v.u >> 16) & 1u);
    return (u16)(r >> 16);
}
__device__ __forceinline__ float bf2f(u16 u) {
    union { unsigned u; float f; } v; v.u = ((unsigned)u) << 16; return v.f;
}
__device__ __forceinline__ unsigned cvt_pk_bf16(float lo, float hi) {
    unsigned r;
    asm("v_cvt_pk_bf16_f32 %0, %1, %2" : "=v"(r) : "v"(lo), "v"(hi));
    return r;
}

#define AS1 __attribute__((address_space(1)))
#define AS3 __attribute__((address_space(3)))
__device__ __forceinline__ void gload_lds16(const void* g, void* l) {
    __builtin_amdgcn_global_load_lds((const AS1 void*)(g), (AS3 void*)(l), 16, 0, 0);
}

// Panel layout (128-row blocks): [panel = R>>7][ktile = k>>5][row = R&127][kk = k&31]

// ---------------- prep: roll(-6,-6) + window partition + cast + PANELIZE (8 elems/thread) ----------------
__global__ __launch_bounds__(256) void prep_x_kernel(const float* __restrict__ x, u16* __restrict__ xw) {
    unsigned i = ((unsigned)blockIdx.x * 256u + threadIdx.x) * 8u;  // 36864*768 total, c % 8 == 0
    int R = (int)(i / 768u); int c = (int)(i % 768u);
    int w = R / 144, nn = R - w * 144;
    int b = w >> 2, wi = w & 3;
    int r = nn / 12, cc = nn - r * 12;
    int sh = (wi >> 1) * 12 + r + 6; if (sh >= 24) sh -= 24;
    int sw = (wi & 1) * 12 + cc + 6; if (sw >= 24) sw -= 24;
    const float* src = x + (((size_t)b * 24 + sh) * 24 + sw) * 768 + c;
    f32x4 v0 = *(const f32x4*)src;
    f32x4 v1 = *(const f32x4*)(src + 4);
    u16x8 o;
    o[0] = f2bf(v0[0]); o[1] = f2bf(v0[1]); o[2] = f2bf(v0[2]); o[3] = f2bf(v0[3]);
    o[4] = f2bf(v1[0]); o[5] = f2bf(v1[1]); o[6] = f2bf(v1[2]); o[7] = f2bf(v1[3]);
    size_t idx = ((size_t)(R >> 7) * 24 + (c >> 5)) * 4096 + (R & 127) * 32 + (c & 31);
    *(u16x8*)(xw + idx) = o;
}

// ---------------- weight transpose + cast + panelize ----------------
__global__ __launch_bounds__(256) void transpose_cast_kernel(const float* __restrict__ w, u16* __restrict__ wt,
                                                             int K, int N) {
    __shared__ float tile[32][33];
    int tx = threadIdx.x & 31, ty = threadIdx.x >> 5;
    int nb = blockIdx.x * 32, kb = blockIdx.y * 32;
#pragma unroll
    for (int rr = 0; rr < 32; rr += 8) tile[rr + ty][tx] = w[(size_t)(kb + rr + ty) * N + nb + tx];
    __syncthreads();
#pragma unroll
    for (int rr = 0; rr < 32; rr += 8) {
        int n = nb + rr + ty, k = kb + tx;
        wt[((size_t)(n >> 7) * 24 + (k >> 5)) * 4096 + (n & 127) * 32 + (k & 31)] = f2bf(tile[tx][rr + ty]);
    }
}

// ---------- bmm[wi][h][m][n] = bf16( rpb[rel[n*144+m]][h] + mask(n,m,wi) ), m=k, n=q ----------
__global__ __launch_bounds__(256) void make_bmm_kernel(const float* __restrict__ tab, const int* __restrict__ rel,
                                                       u16* __restrict__ bmm) {
    int i = blockIdx.x * 256 + threadIdx.x;  // 4*24*20736 = 1,990,656
    if (i >= 1990656) return;
    int wiH = i / 20736, mn = i - wiH * 20736;
    int wi = wiH / 24, h = wiH - wi * 24;
    int m = mn / 144, n = mn - m * 144;
    int wh = wi >> 1, ww = wi & 1;
    int rn = n / 12, cn = n - rn * 12;
    int rm = m / 12, cm = m - rm * 12;
    int regn = (wh ? (rn < 6 ? 1 : 2) : 0) * 3 + (ww ? (cn < 6 ? 1 : 2) : 0);
    int regm = (wh ? (rm < 6 ? 1 : 2) : 0) * 3 + (ww ? (cm < 6 ? 1 : 2) : 0);
    float v = tab[rel[n * 144 + m] * 24 + h];
    if (regn != regm) v -= 100.0f;
    bmm[i] = f2bf(v);
}

// ------- 128x128 BK=32, 4 waves, 3 buffers x 16KB, 3 blocks/CU, depth-2, PERSISTENT tiles -------
#define FENCE asm volatile("" ::: "memory")
#define BARRIER __builtin_amdgcn_s_barrier()

#define STAGE_TILE(gp, ldsoff)                                                                 \
    { const char* srcb = (const char*)(gp);                                                    \
      _Pragma("unroll") for (int j = 0; j < 2; j++) {                                          \
        int off = j * 4096 + t * 16;                                                           \
        gload_lds16(srcb + off, (char*)lds + (ldsoff) + off);                                  \
    } }

template <int EPI>
__global__ __launch_bounds__(256, 3) void gemm128_kernel(const u16* __restrict__ A, const u16* __restrict__ Bt,
                                                         const float* __restrict__ bias,
                                                         u16* __restrict__ o0, u16* __restrict__ o1, u16* __restrict__ o2,
                                                         int Ndim, int Kdim, int nxb, int ntiles, float qscale) {
    __shared__ __align__(16) u16 lds[24576];
    const int t = threadIdx.x, lane = t & 63, wv = t >> 6;
    const int wr = wv >> 1, wc = wv & 1;
    const int l15 = lane & 15, lg = lane >> 4;
    const int NT = Kdim >> 5;
    const int q8 = ntiles >> 3, r8 = ntiles & 7;

    int tid = blockIdx.x;
    int xcd = tid & 7, loc = tid >> 3;
    int wg = (xcd < r8 ? xcd * (q8 + 1) : r8 * (q8 + 1) + (xcd - r8) * q8) + loc;
    int by = wg / nxb, bx = wg - by * nxb;
    const u16* Ap = A + (size_t)by * NT * 4096;
    const u16* Bp = Bt + (size_t)bx * NT * 4096;

    STAGE_TILE(Ap, 0);
    STAGE_TILE(Bp, 8192);
    STAGE_TILE(Ap + 4096, 16384);
    STAGE_TILE(Bp + 4096, 16384 + 8192);
    asm volatile("s_waitcnt vmcnt(4)" ::: "memory");
    FENCE; BARRIER;

    while (true) {
        f32x4 acc[4][4] = {};
        int ntid = tid + (int)gridDim.x;
        bool hasNext = ntid < ntiles;
        int nby = 0, nbx = 0;
        const u16 *Anp = nullptr, *Bnp = nullptr;
        if (hasNext) {
            int nxcd = ntid & 7, nloc = ntid >> 3;
            int nwg = (nxcd < r8 ? nxcd * (q8 + 1) : r8 * (q8 + 1) + (nxcd - r8) * q8) + nloc;
            nby = nwg / nxb; nbx = nwg - nby * nxb;
            Anp = A + (size_t)nby * NT * 4096;
            Bnp = Bt + (size_t)nbx * NT * 4096;
        }
        for (int T = 0; T < NT; ++T) {
            const char* rb = (const char*)lds + (T % 3) * 16384;
            const int sb = ((T + 2) % 3) * 16384;
            bool st = true;
            if (T + 2 < NT) {
                STAGE_TILE(Ap + (T + 2) * 4096, sb);
                STAGE_TILE(Bp + (T + 2) * 4096, sb + 8192);
            } else if (hasNext) {
                int TT = T + 2 - NT;
                STAGE_TILE(Anp + TT * 4096, sb);
                STAGE_TILE(Bnp + TT * 4096, sb + 8192);
            } else st = false;
            bf16x8 aR[4], bR[4];
#pragma unroll
            for (int mf = 0; mf < 4; mf++)
                aR[mf] = *(const bf16x8*)(rb + (wr * 64 + mf * 16 + l15) * 64 + lg * 16);
#pragma unroll
            for (int nf = 0; nf < 4; nf++)
                bR[nf] = *(const bf16x8*)(rb + 8192 + (wc * 64 + nf * 16 + l15) * 64 + lg * 16);
            __builtin_amdgcn_s_setprio(1);
#pragma unroll
            for (int mf = 0; mf < 4; mf++)
#pragma unroll
                for (int nf = 0; nf < 4; nf++)
                    acc[mf][nf] = __builtin_amdgcn_mfma_f32_16x16x32_bf16(aR[mf], bR[nf], acc[mf][nf], 0, 0, 0);
            __builtin_amdgcn_s_setprio(0);
            if (T < NT - 1 || hasNext) {
                if (st) { asm volatile("s_waitcnt vmcnt(4)" ::: "memory"); }
                else    { asm volatile("s_waitcnt vmcnt(0)" ::: "memory"); }
                FENCE; BARRIER;
            }
        }
        const int bm = by << 7, bn = bx << 7;
#pragma unroll
        for (int mf = 0; mf < 4; mf++) {
            int Rbase = bm + wr * 64 + mf * 16 + lg * 4;
#pragma unroll
            for (int nf = 0; nf < 4; nf++) {
                int Cg = bn + wc * 64 + nf * 16 + l15;
                float bv = bias[Cg];
                if (EPI == 0) {
                    int s = Cg / 768; int rem = Cg - s * 768; int h = rem >> 5; int dd = rem & 31;
#pragma unroll
                    for (int rg = 0; rg < 4; rg++) {
                        int R = Rbase + rg;
                        int w2 = R / 144; int nn = R - w2 * 144;
                        float v = acc[mf][nf][rg] + bv;
                        if (s == 0)      o0[((size_t)(w2 * 24 + h) * 144 + nn) * 32 + dd] = f2bf(v * qscale);
                        else if (s == 1) o1[((size_t)(w2 * 24 + h) * 144 + nn) * 32 + dd] = f2bf(v);
                        else             o2[((size_t)(w2 * 24 + h) * 32 + dd) * 144 + nn] = f2bf(v);
                    }
                } else {
#pragma unroll
                    for (int rg = 0; rg < 4; rg++) {
                        int R = Rbase + rg;
                        o0[(size_t)R * Ndim + Cg] = f2bf(acc[mf][nf][rg] + bv);
                    }
                }
            }
        }
        if (!hasNext) break;
        tid = ntid; by = nby; bx = nbx; Ap = Anp; Bp = Bnp;
    }
}

// ---- fused window attention, SWAPPED operands; bias+mask pre-fused in bmm[wi][h][k][q] ----
__global__ __launch_bounds__(192) void attn_kernel(const u16* __restrict__ Qg, const u16* __restrict__ Kg,
                                                   const u16* __restrict__ Vg, const u16* __restrict__ bmm,
                                                   u16* __restrict__ Ob) {
    __shared__ __align__(16) u16 Ks[144 * 40];
    __shared__ __align__(16) u16 Vs[32 * 160];
    const int bx = blockIdx.x;
    const int w = bx / 24, h = bx - w * 24;
    const int wi = w & 3;
    const int t = threadIdx.x, lane = t & 63, wv = t >> 6;
    const int l15 = lane & 15, lg = lane >> 4;
    const size_t base = (size_t)bx * 4608;
#pragma unroll
    for (int p = 0; p < 3; p++) {
        int e = t + p * 192;
        int row = e >> 2, cx = (e & 3) << 3;
        *(u16x8*)(Ks + row * 40 + cx) = *(const u16x8*)(Kg + base + row * 32 + cx);
        int rv = e / 18, cv = (e - rv * 18) * 8;
        int ba = (rv * 320 + cv * 2) ^ ((rv & 7) << 4);
        *(u16x8*)((char*)Vs + ba) = *(const u16x8*)(Vg + base + rv * 144 + cv);
    }
    if (t < 64) {
        u16x8 zz = (u16x8)0;
        int rv = t >> 1, cv = 144 + (t & 1) * 8;
        int ba = (rv * 320 + cv * 2) ^ ((rv & 7) << 4);
        *(u16x8*)((char*)Vs + ba) = zz;
    }
    __syncthreads();

    const u16* bh = bmm + (size_t)(wi * 24 + h) * 20736;
#pragma unroll 1
    for (int it = 0; it < 3; ++it) {
        const int s = wv * 3 + it;
        const int q = s * 16 + l15;
        bf16x8 aq = *(const bf16x8*)(Qg + base + (size_t)q * 32 + lg * 8);
        f32x4 S[9];
        {
            f32x4 z4 = (f32x4)0.0f;
#pragma unroll
            for (int j = 0; j < 9; j++) {
                bf16x8 bk = *(const bf16x8*)(Ks + (j * 16 + l15) * 40 + lg * 8);
                S[j] = __builtin_amdgcn_mfma_f32_16x16x32_bf16(bk, aq, z4, 0, 0, 0);
            }
        }
        float mx = -1e30f;
#pragma unroll
        for (int j = 0; j < 9; j++) {
            const u16* bj = bh + (j * 16 + lg * 4) * 144 + q;
#pragma unroll
            for (int rg = 0; rg < 4; rg++) {
                float v = S[j][rg] + bf2f(bj[rg * 144]);
                S[j][rg] = v;
                mx = fmaxf(mx, v);
            }
        }
        mx = fmaxf(mx, __shfl_xor(mx, 16));
        mx = fmaxf(mx, __shfl_xor(mx, 32));
        float sum = 0.0f;
#pragma unroll
        for (int j = 0; j < 9; j++) {
#pragma unroll
            for (int rg = 0; rg < 4; rg++) { float e = __expf(S[j][rg] - mx); S[j][rg] = e; sum += e; }
        }
        sum += __shfl_xor(sum, 16);
        sum += __shfl_xor(sum, 32);
        float inv = 1.0f / sum;
        unsigned pk[10][2];
#pragma unroll
        for (int j = 0; j < 9; j++) {
            pk[j][0] = cvt_pk_bf16(S[j][0], S[j][1]);
            pk[j][1] = cvt_pk_bf16(S[j][2], S[j][3]);
        }
        pk[9][0] = 0; pk[9][1] = 0;
        f32x4 o0 = (f32x4)0.0f, o1 = (f32x4)0.0f;
        const int srcA = 32 * (lg & 1) + l15;
        const int srcB = srcA + 16;
        const bool lowj = (lg < 2);
#pragma unroll
        for (int ks = 0; ks < 5; ks++) {
            const int j0 = 2 * ks, j1 = 2 * ks + 1;
            unsigned a0 = __shfl(pk[j0][0], srcA), a1 = __shfl(pk[j0][1], srcA);
            unsigned a2 = __shfl(pk[j0][0], srcB), a3 = __shfl(pk[j0][1], srcB);
            unsigned b0 = __shfl(pk[j1][0], srcA), b1 = __shfl(pk[j1][1], srcA);
            unsigned b2 = __shfl(pk[j1][0], srcB), b3 = __shfl(pk[j1][1], srcB);
            u32x4 pw;
            pw[0] = lowj ? a0 : b0; pw[1] = lowj ? a1 : b1;
            pw[2] = lowj ? a2 : b2; pw[3] = lowj ? a3 : b3;
            bf16x8 pb = *(const bf16x8*)&pw;
            int k2 = (ks * 32 + lg * 8) * 2;
            int rv0 = l15, rv1 = 16 + l15;
            bf16x8 v0 = *(const bf16x8*)((char*)Vs + ((rv0 * 320 + k2) ^ ((rv0 & 7) << 4)));
            bf16x8 v1 = *(const bf16x8*)((char*)Vs + ((rv1 * 320 + k2) ^ ((rv1 & 7) << 4)));
            o0 = __builtin_amdgcn_mfma_f32_16x16x32_bf16(v0, pb, o0, 0, 0, 0);
            o1 = __builtin_amdgcn_mfma_f32_16x16x32_bf16(v1, pb, o1, 0, 0, 0);
        }
        int R = w * 144 + q;
        size_t idx = ((size_t)(R >> 7) * 24 + h) * 4096 + (R & 127) * 32 + lg * 4;
        u16x4 w0, w1;
#pragma unroll
        for (int rg = 0; rg < 4; rg++) { w0[rg] = f2bf(o0[rg] * inv); w1[rg] = f2bf(o1[rg] * inv); }
        *(u16x4*)(Ob + idx) = w0;
        *(u16x4*)(Ob + idx + 16) = w1;
    }
}

// ---------------- L2 norm (bf16 input) + window-merge + reverse shift ----------------
__global__ __launch_bounds__(256) void norm_kernel(const u16* __restrict__ raw, float* __restrict__ out) {
    int R = blockIdx.x * 4 + (threadIdx.x >> 6);
    int lane = threadIdx.x & 63;
    const u16* src = raw + (size_t)R * 768;
    u16x8 a = *(const u16x8*)(src + lane * 8);
    u16x4 b = *(const u16x4*)(src + 512 + lane * 4);
    float f[12];
#pragma unroll
    for (int k = 0; k < 8; k++) f[k] = bf2f(a[k]);
#pragma unroll
    for (int k = 0; k < 4; k++) f[8 + k] = bf2f(b[k]);
    float ss = 0.0f;
#pragma unroll
    for (int k = 0; k < 12; k++) ss += f[k] * f[k];
#pragma unroll
    for (int d = 1; d < 64; d <<= 1) ss += __shfl_xor(ss, d);
    float inv = 1.0f / sqrtf(ss + 1e-6f);
    int w = R / 144, nn = R - w * 144;
    int bb = w >> 2, wi = w & 3;
    int r = nn / 12, cc = nn - r * 12;
    int oh = (wi >> 1) * 12 + r + 6; if (oh >= 24) oh -= 24;
    int ow = (wi & 1) * 12 + cc + 6; if (ow >= 24) ow -= 24;
    float* dst = out + (((size_t)bb * 24 + oh) * 24 + ow) * 768;
    f32x4 v0, v1, v2;
#pragma unroll
    for (int k = 0; k < 4; k++) { v0[k] = f[k] * inv; v1[k] = f[4 + k] * inv; v2[k] = f[8 + k] * inv; }
    *(f32x4*)(dst + lane * 8) = v0;
    *(f32x4*)(dst + lane * 8 + 4) = v1;
    *(f32x4*)(dst + 512 + lane * 4) = v2;
}

extern "C" void kernel_launch(void* const* d_in, const int* in_sizes, int n_in,
                              void* d_out, int out_size, void* d_ws, size_t ws_size,
                              hipStream_t stream) {
    const float* x      = (const float*)d_in[0];
    const float* qkv_w  = (const float*)d_in[1];
    const float* qkv_b  = (const float*)d_in[2];
    const float* proj_w = (const float*)d_in[3];
    const float* proj_b = (const float*)d_in[4];
    const float* rpb    = (const float*)d_in[5];
    const int*   rel    = (const int*)d_in[6];

    char* ws = (char*)d_ws;
    const size_t SZ = 56623104;  // 36864*768*2 bytes
    u16*   xw   = (u16*)(ws);
    u16*   Qb   = (u16*)(ws + SZ);
    u16*   Kb   = (u16*)(ws + 2 * SZ);
    u16*   Vt   = (u16*)(ws + 3 * SZ);
    u16*   Ob   = (u16*)(ws + 4 * SZ);
    u16*   qwt  = (u16*)(ws + 5 * SZ);
    u16*   pwt  = (u16*)(ws + 5 * SZ + 3538944);
    u16*   bmm  = (u16*)(ws);   // built AFTER QKV GEMM into dead xw space
    u16*   raw16 = (u16*)(ws);  // aliases bmm/xw (dead by GEMM2)

    prep_x_kernel<<<13824, 256, 0, stream>>>(x, xw);
    transpose_cast_kernel<<<dim3(72, 24), 256, 0, stream>>>(qkv_w, qwt, 768, 2304);
    transpose_cast_kernel<<<dim3(24, 24), 256, 0, stream>>>(proj_w, pwt, 768, 768);

    gemm128_kernel<0><<<768, 256, 0, stream>>>(xw, qwt, qkv_b, Qb, Kb, Vt,
                                               2304, 768, 18, 5184, 0.17677669529663687f);
    make_bmm_kernel<<<7776, 256, 0, stream>>>(rpb, rel, bmm);
    attn_kernel<<<6144, 192, 0, stream>>>(Qb, Kb, Vt, bmm, Ob);
    gemm128_kernel<1><<<768, 256, 0, stream>>>(Ob, pwt, proj_b, raw16, nullptr, nullptr,
                                               768, 768, 6, 1728, 1.0f);
    norm_kernel<<<9216, 256, 0, stream>>>(raw16, (float*)d_out);
}